// Round 1
// baseline (238.608 us; speedup 1.0000x reference)
//
#include <hip/hip_runtime.h>
#include <hip/hip_bf16.h>

// upfirdn2d: UP=1, DOWN=2, PAD=5, 12x12 separable kernel (sym6 outer product).
// Fused separable stride-2 FIR: per block, stage a 74x74 input tile in LDS,
// vertical 12-tap pass (rows already downsampled) into LDS intermediate,
// horizontal 12-tap pass + downsample, write 32x32 output tile.

#define OT   32            // output tile (square)
#define IT   (2*OT + 10)   // input tile incl. halo = 74
#define LSTR 75            // LDS row stride (odd -> 2-way max bank aliasing)
#define H_IN  256
#define W_IN  256
#define H_OUT 128
#define W_OUT 128
#define KTAP 12

__global__ __launch_bounds__(256)
void upfirdn2d_sym6(const float* __restrict__ x,
                    const float* __restrict__ k2d,
                    float* __restrict__ out) {
    __shared__ float xs[IT * LSTR];   // 74 x 75
    __shared__ float vs[OT * LSTR];   // 32 x 75
    __shared__ float ks[KTAP * KTAP]; // raw 12x12 kernel
    __shared__ float w[KTAP];         // flipped separable taps

    const int tid = threadIdx.x;

    // Stage raw 2D kernel (cheap, L1/L2-cached across blocks)
    if (tid < KTAP * KTAP) ks[tid] = k2d[tid];

    const int img = blockIdx.y;           // 0..1023 (B*C images)
    const int ti  = blockIdx.x >> 2;      // tile row 0..3
    const int tj  = blockIdx.x & 3;       // tile col 0..3

    const float* xim = x + (size_t)img * (H_IN * W_IN);

    const int r0 = ti * (2 * OT) - 5;     // global row of xs row 0
    const int c0 = tj * (2 * OT) - 5;     // global col of xs col 0

    // Stage input tile with zero-padding at image borders
    for (int idx = tid; idx < IT * IT; idx += 256) {
        const int r  = idx / IT;
        const int c  = idx - r * IT;
        const int gr = r0 + r;
        const int gc = c0 + c;
        float v = 0.0f;
        if ((unsigned)gr < (unsigned)H_IN && (unsigned)gc < (unsigned)W_IN)
            v = xim[gr * W_IN + gc];
        xs[r * LSTR + c] = v;
    }
    __syncthreads();

    // Derive flipped separable taps from the 2D kernel:
    // k2d[p][q] = h[p]*h[q]; rowsum[p] = h[p]*S, total = S^2 (S = sum h > 0)
    // flipped tap w[p] = h[11-p] = rowsum[11-p] / sqrt(total)
    if (tid < KTAP) {
        float tot = 0.0f;
        #pragma unroll
        for (int i = 0; i < KTAP * KTAP; ++i) tot += ks[i];
        float rs = 0.0f;
        #pragma unroll
        for (int q = 0; q < KTAP; ++q) rs += ks[(KTAP - 1 - tid) * KTAP + q];
        w[tid] = rs * rsqrtf(tot);
    }
    __syncthreads();

    // Vertical pass: v[i][c] = sum_p w[p] * xs[2i+p][c]
    for (int idx = tid; idx < OT * IT; idx += 256) {
        const int i = idx / IT;
        const int c = idx - i * IT;
        float acc = 0.0f;
        #pragma unroll
        for (int p = 0; p < KTAP; ++p)
            acc += w[p] * xs[(2 * i + p) * LSTR + c];
        vs[i * LSTR + c] = acc;
    }
    __syncthreads();

    // Horizontal pass + downsample + store
    float* oim = out + (size_t)img * (H_OUT * W_OUT);
    const int oi0 = ti * OT;
    const int oj0 = tj * OT;
    for (int idx = tid; idx < OT * OT; idx += 256) {
        const int i = idx >> 5;
        const int j = idx & 31;
        float acc = 0.0f;
        #pragma unroll
        for (int q = 0; q < KTAP; ++q)
            acc += w[q] * vs[i * LSTR + 2 * j + q];
        oim[(oi0 + i) * W_OUT + oj0 + j] = acc;
    }
}

extern "C" void kernel_launch(void* const* d_in, const int* in_sizes, int n_in,
                              void* d_out, int out_size, void* d_ws, size_t ws_size,
                              hipStream_t stream) {
    const float* x   = (const float*)d_in[0];
    const float* k2d = (const float*)d_in[1];
    float* out       = (float*)d_out;

    // B*C = 16*64 = 1024 images; 128/32 = 4 tiles per dim -> 16 tiles/image
    dim3 grid(16, 1024);
    dim3 block(256);
    upfirdn2d_sym6<<<grid, block, 0, stream>>>(x, k2d, out);
}

// Round 2
// 87.766 us; speedup vs baseline: 2.7187x; 2.7187x over previous
//
#include <hip/hip_runtime.h>

// upfirdn2d: UP=1, DOWN=2, PAD=5, 12x12 separable sym6 kernel.
// Streaming separable design:
//   - vertical 12-tap pass reads x directly from global (float4, register
//     sliding window, 8 out-rows per thread), writes 64x148 f32 LDS tile
//   - horizontal 12-tap pass + downsample reads LDS (b128), writes out
// No input LDS tile; all LDS traffic is b128; no integer division.

#define H_IN  256
#define W_IN  256
#define H_OUT 128
#define W_OUT 128
#define KTAP  12
#define OTR   64    // output tile rows per block
#define OTC   64    // output tile cols per block
#define VSTR  148   // vs row stride (floats); 148%32=20 spreads banks evenly

__global__ __launch_bounds__(256)
void upfirdn2d_sym6(const float* __restrict__ x,
                    const float* __restrict__ k2d,
                    float* __restrict__ out) {
    __shared__ float vs[OTR * VSTR];   // 64 x 148 x 4B = 37.9 KB
    __shared__ float ks[KTAP * KTAP];
    __shared__ float wsh[KTAP];

    const int tid = threadIdx.x;

    // --- derive flipped separable taps from the 12x12 outer-product kernel
    if (tid < KTAP * KTAP) ks[tid] = k2d[tid];
    __syncthreads();
    if (tid < KTAP) {
        float tot = 0.f;
        #pragma unroll
        for (int i = 0; i < KTAP * KTAP; ++i) tot += ks[i];
        float rs = 0.f;
        #pragma unroll
        for (int q = 0; q < KTAP; ++q) rs += ks[(KTAP - 1 - tid) * KTAP + q];
        wsh[tid] = rs * rsqrtf(tot);   // w[p] = h[11-p]
    }
    __syncthreads();
    float w[KTAP];
    #pragma unroll
    for (int p = 0; p < KTAP; ++p) w[p] = wsh[p];

    const int img = blockIdx.y;            // 0..1023
    const int ti  = blockIdx.x >> 1;       // row tile 0..1
    const int tj  = blockIdx.x & 1;        // col tile 0..1
    const float* xim = x + (size_t)img * (H_IN * W_IN);

    // aligned column frame: frame word f <-> global col gc0 + f
    const int gc0     = 128 * tj - 8;      // 4-aligned (input col base -5, minus 3)
    const int gr_base = 128 * ti;

    // ---- vertical pass: 288 tasks (rg 0..7 x cg 0..35), each 8 rows x 4 cols
    for (int t = tid; t < 288; t += 256) {
        const int rg  = t / 36;            // small constant-divisor, compiler magic-muls
        const int cg  = t - rg * 36;
        const int col = gc0 + 4 * cg;                       // global col of this float4
        const bool colok = (unsigned)col < (unsigned)W_IN;  // groups are fully in/out
        const int i0  = rg * 8;                             // local out-row base
        const int gr0 = gr_base + 2 * i0 - 5;               // first input row of window

        float4 acc[8];
        #pragma unroll
        for (int k = 0; k < 8; ++k) acc[k] = make_float4(0.f, 0.f, 0.f, 0.f);

        #pragma unroll
        for (int rr = 0; rr < 26; ++rr) {
            const int gr = gr0 + rr;
            float4 v = make_float4(0.f, 0.f, 0.f, 0.f);
            if (colok && (unsigned)gr < (unsigned)H_IN)
                v = *reinterpret_cast<const float4*>(xim + gr * W_IN + col);
            #pragma unroll
            for (int ri = 0; ri < 8; ++ri) {
                const int p = rr - 2 * ri;                  // tap index, compile-time
                if (p >= 0 && p < KTAP) {
                    acc[ri].x = fmaf(w[p], v.x, acc[ri].x);
                    acc[ri].y = fmaf(w[p], v.y, acc[ri].y);
                    acc[ri].z = fmaf(w[p], v.z, acc[ri].z);
                    acc[ri].w = fmaf(w[p], v.w, acc[ri].w);
                }
            }
        }
        #pragma unroll
        for (int ri = 0; ri < 8; ++ri)
            *reinterpret_cast<float4*>(&vs[(i0 + ri) * VSTR + 4 * cg]) = acc[ri];
    }
    __syncthreads();

    // ---- horizontal pass: 512 tasks (i 0..63 x g 0..7), 8 outputs each
    float* oim = out + (size_t)img * (H_OUT * W_OUT);
    #pragma unroll
    for (int t = tid; t < 512; t += 256) {
        const int i = t >> 3;
        const int g = t & 7;

        float f[32];
        #pragma unroll
        for (int m = 0; m < 8; ++m) {
            float4 v4 = *reinterpret_cast<const float4*>(&vs[i * VSTR + 16 * g + 4 * m]);
            f[4*m+0] = v4.x; f[4*m+1] = v4.y; f[4*m+2] = v4.z; f[4*m+3] = v4.w;
        }
        // output j = 8g+jj needs frame words 16g + 2jj+3 .. 16g + 2jj+14
        float o[8];
        #pragma unroll
        for (int jj = 0; jj < 8; ++jj) {
            float a = 0.f;
            #pragma unroll
            for (int q = 0; q < KTAP; ++q)
                a = fmaf(w[q], f[2*jj + 3 + q], a);
            o[jj] = a;
        }
        const int orow = ti * OTR + i;
        const int ocol = tj * OTC + 8 * g;
        *reinterpret_cast<float4*>(oim + orow * W_OUT + ocol)     = make_float4(o[0], o[1], o[2], o[3]);
        *reinterpret_cast<float4*>(oim + orow * W_OUT + ocol + 4) = make_float4(o[4], o[5], o[6], o[7]);
    }
}

extern "C" void kernel_launch(void* const* d_in, const int* in_sizes, int n_in,
                              void* d_out, int out_size, void* d_ws, size_t ws_size,
                              hipStream_t stream) {
    const float* x   = (const float*)d_in[0];
    const float* k2d = (const float*)d_in[1];
    float* out       = (float*)d_out;

    // 2x2 tiles of 64x64 outputs per image, 1024 images
    dim3 grid(4, 1024);
    dim3 block(256);
    upfirdn2d_sym6<<<grid, block, 0, stream>>>(x, k2d, out);
}

// Round 3
// 79.603 us; speedup vs baseline: 2.9975x; 1.1025x over previous
//
#include <hip/hip_runtime.h>

// upfirdn2d: UP=1, DOWN=2, PAD=5, 12x12 separable sym6 kernel.
// v3: 32x64 output tile, 192 threads.
//   - vertical pass: 144 tasks (<=1 per thread -> no pre-barrier wave imbalance),
//     each 8 out-rows x 4 cols, float4 global reads, register sliding window
//   - 19 KB LDS intermediate -> 8 blocks/CU for cross-block phase overlap
//   - horizontal pass: 256 tasks, tail imbalance after last barrier (harmless)

#define H_IN  256
#define W_IN  256
#define H_OUT 128
#define W_OUT 128
#define KTAP  12
#define OTR   32    // output tile rows
#define OTC   64    // output tile cols
#define VSTR  148   // vs row stride (words); spreads banks, min-conflict
#define NTHR  192

__global__ __launch_bounds__(NTHR)
void upfirdn2d_sym6(const float* __restrict__ x,
                    const float* __restrict__ k2d,
                    float* __restrict__ out) {
    __shared__ float vs[OTR * VSTR];   // 32 x 148 x 4B = 18.5 KB
    __shared__ float ks[KTAP * KTAP];
    __shared__ float wsh[KTAP];

    const int tid = threadIdx.x;

    // --- derive flipped separable taps from the 12x12 outer-product kernel
    if (tid < KTAP * KTAP) ks[tid] = k2d[tid];
    __syncthreads();
    if (tid < KTAP) {
        float tot = 0.f;
        #pragma unroll
        for (int i = 0; i < KTAP * KTAP; ++i) tot += ks[i];
        float rs = 0.f;
        #pragma unroll
        for (int q = 0; q < KTAP; ++q) rs += ks[(KTAP - 1 - tid) * KTAP + q];
        wsh[tid] = rs * rsqrtf(tot);   // w[p] = h[11-p]
    }
    __syncthreads();
    float w[KTAP];
    #pragma unroll
    for (int p = 0; p < KTAP; ++p) w[p] = wsh[p];   // LDS broadcast reads

    const int img = blockIdx.y;            // 0..1023
    const int ti  = blockIdx.x >> 1;       // row tile 0..3 (32 out rows each)
    const int tj  = blockIdx.x & 1;        // col tile 0..1 (64 out cols each)
    const float* xim = x + (size_t)img * (H_IN * W_IN);

    const int gc0 = 128 * tj - 8;          // global col of frame word 0 (4-aligned)
    const bool edge_rows = (ti == 0) || (ti == 3);   // block-uniform

    // ---- vertical pass: 144 tasks (rg 0..3 x cg 0..35), 8 out-rows x 4 cols each
    if (tid < 144) {
        const int rg  = tid / 36;                       // magic-mul const divide
        const int cg  = tid - rg * 36;
        const int col = gc0 + 4 * cg;
        const bool colok = (unsigned)col < (unsigned)W_IN;  // lane-constant
        const int i0  = rg * 8;
        const int gr0 = 64 * ti + 16 * rg - 5;          // first input row of window

        float4 acc[8];
        #pragma unroll
        for (int k = 0; k < 8; ++k) acc[k] = make_float4(0.f, 0.f, 0.f, 0.f);

        if (!edge_rows) {
            const float* rp = xim + (size_t)gr0 * W_IN + col;
            #pragma unroll
            for (int rr = 0; rr < 26; ++rr) {
                float4 v = make_float4(0.f, 0.f, 0.f, 0.f);
                if (colok) v = *reinterpret_cast<const float4*>(rp);
                rp += W_IN;
                #pragma unroll
                for (int ri = 0; ri < 8; ++ri) {
                    const int p = rr - 2 * ri;          // compile-time tap index
                    if (p >= 0 && p < KTAP) {
                        acc[ri].x = fmaf(w[p], v.x, acc[ri].x);
                        acc[ri].y = fmaf(w[p], v.y, acc[ri].y);
                        acc[ri].z = fmaf(w[p], v.z, acc[ri].z);
                        acc[ri].w = fmaf(w[p], v.w, acc[ri].w);
                    }
                }
            }
        } else {
            #pragma unroll
            for (int rr = 0; rr < 26; ++rr) {
                const int gr = gr0 + rr;
                float4 v = make_float4(0.f, 0.f, 0.f, 0.f);
                if (colok && (unsigned)gr < (unsigned)H_IN)
                    v = *reinterpret_cast<const float4*>(xim + gr * W_IN + col);
                #pragma unroll
                for (int ri = 0; ri < 8; ++ri) {
                    const int p = rr - 2 * ri;
                    if (p >= 0 && p < KTAP) {
                        acc[ri].x = fmaf(w[p], v.x, acc[ri].x);
                        acc[ri].y = fmaf(w[p], v.y, acc[ri].y);
                        acc[ri].z = fmaf(w[p], v.z, acc[ri].z);
                        acc[ri].w = fmaf(w[p], v.w, acc[ri].w);
                    }
                }
            }
        }
        #pragma unroll
        for (int ri = 0; ri < 8; ++ri)
            *reinterpret_cast<float4*>(&vs[(i0 + ri) * VSTR + 4 * cg]) = acc[ri];
    }
    __syncthreads();

    // ---- horizontal pass: 256 tasks (i 0..31 x g 0..7), 8 outputs each.
    // Tail imbalance (wave 0 does 2 tasks) is after the last barrier -> harmless.
    float* oim = out + (size_t)img * (H_OUT * W_OUT);
    for (int t = tid; t < 256; t += NTHR) {
        const int i = t >> 3;
        const int g = t & 7;

        float f[32];
        #pragma unroll
        for (int m = 0; m < 8; ++m) {
            float4 v4 = *reinterpret_cast<const float4*>(&vs[i * VSTR + 16 * g + 4 * m]);
            f[4*m+0] = v4.x; f[4*m+1] = v4.y; f[4*m+2] = v4.z; f[4*m+3] = v4.w;
        }
        // output j = 8g+jj needs frame words 16g + 2jj+3 .. 16g + 2jj+14
        float o[8];
        #pragma unroll
        for (int jj = 0; jj < 8; ++jj) {
            float a = 0.f;
            #pragma unroll
            for (int q = 0; q < KTAP; ++q)
                a = fmaf(w[q], f[2*jj + 3 + q], a);
            o[jj] = a;
        }
        const int orow = ti * OTR + i;
        const int ocol = tj * OTC + 8 * g;
        *reinterpret_cast<float4*>(oim + orow * W_OUT + ocol)     = make_float4(o[0], o[1], o[2], o[3]);
        *reinterpret_cast<float4*>(oim + orow * W_OUT + ocol + 4) = make_float4(o[4], o[5], o[6], o[7]);
    }
}

extern "C" void kernel_launch(void* const* d_in, const int* in_sizes, int n_in,
                              void* d_out, int out_size, void* d_ws, size_t ws_size,
                              hipStream_t stream) {
    const float* x   = (const float*)d_in[0];
    const float* k2d = (const float*)d_in[1];
    float* out       = (float*)d_out;

    // 4x2 tiles of 32x64 outputs per image, 1024 images
    dim3 grid(8, 1024);
    dim3 block(NTHR);
    upfirdn2d_sym6<<<grid, block, 0, stream>>>(x, k2d, out);
}